// Round 1
// baseline (832.001 us; speedup 1.0000x reference)
//
#include <hip/hip_runtime.h>
#include <hip/hip_bf16.h>
#include <cstdint>

// MFMA fragment types (per cdna_hip_programming.md §3, compile-verified form)
typedef __attribute__((ext_vector_type(8))) short short8;   // 8 bf16 = 4 VGPRs
typedef __attribute__((ext_vector_type(4))) float floatx4;  // 4 fp32 acc

#define LEAKY_ALPHA 0.2f

__device__ __forceinline__ unsigned short f2bf_rne(float f) {
    unsigned u = __float_as_uint(f);
    unsigned r = u + 0x7FFFu + ((u >> 16) & 1u);   // round-to-nearest-even
    return (unsigned short)(r >> 16);
}

// ---------------------------------------------------------------------------
// Kernel 1: h = inp @ W  (fp32), s1 = h·a1, s2 = h·a2, and hT bf16 [b][n][j]
// grid 512 (8 b × 64 row-tiles of 64), block 256 (4 waves; wave handles 16 rows)
// ---------------------------------------------------------------------------
__global__ __launch_bounds__(256) void k_h(const float* __restrict__ inp,
                                           const float* __restrict__ W,
                                           const float* __restrict__ a,
                                           unsigned short* __restrict__ hT,
                                           float* __restrict__ s1,
                                           float* __restrict__ s2) {
    __shared__ float hs[64][65];   // +1 pad: transpose-read 2-way max (free)
    const int tid  = threadIdx.x;
    const int wv   = tid >> 6;
    const int lane = tid & 63;
    const int blk  = blockIdx.x;
    const int b     = blk >> 6;         // 0..7
    const int ibase = (blk & 63) * 64;  // row tile base

    const float a1 = a[lane];
    const float a2 = a[64 + lane];

    for (int rr = 0; rr < 16; ++rr) {
        const int rloc = wv * 16 + rr;
        const int row  = ibase + rloc;
        const float* ip = inp + ((size_t)(b * 4096 + row)) * 128;  // wave-uniform
        float acc = 0.f;
        #pragma unroll
        for (int f = 0; f < 128; f += 4) {
            float4 v = *(const float4*)(ip + f);   // uniform addr -> s_load
            acc += v.x * W[(f + 0) * 64 + lane];
            acc += v.y * W[(f + 1) * 64 + lane];
            acc += v.z * W[(f + 2) * 64 + lane];
            acc += v.w * W[(f + 3) * 64 + lane];
        }
        hs[rloc][lane] = acc;
        float r1 = acc * a1;
        float r2 = acc * a2;
        #pragma unroll
        for (int off = 32; off > 0; off >>= 1) {
            r1 += __shfl_xor(r1, off);
            r2 += __shfl_xor(r2, off);
        }
        if (lane == 0) {
            s1[b * 4096 + row] = r1;
            s2[b * 4096 + row] = r2;
        }
    }
    __syncthreads();

    // transpose-write hT[b][n][ibase..ibase+63] in bf16, coalesced 32 B/thread
    const int n  = tid >> 2;  // 0..63
    const int iq = tid & 3;   // 0..3 -> 16 i's each
    unsigned pk[8];
    #pragma unroll
    for (int s = 0; s < 16; s += 2) {
        unsigned lo = f2bf_rne(hs[iq * 16 + s    ][n]);
        unsigned hi = f2bf_rne(hs[iq * 16 + s + 1][n]);
        pk[s >> 1] = lo | (hi << 16);
    }
    unsigned short* dst = hT + ((size_t)(b * 64 + n)) * 4096 + ibase + iq * 16;
    *(int4*)(dst)     = *(int4*)&pk[0];
    *(int4*)(dst + 8) = *(int4*)&pk[4];
}

// ---------------------------------------------------------------------------
// Kernel 2: flash-style masked softmax + PV via MFMA.
// grid 1024 (8 b × 128 row-tiles of 32), block 256 = 4 waves.
// wave w: rows rtile*32 + (w&1)*16 .. +15, j-half = w>>1 (2048 j's, 64 K-steps)
// ---------------------------------------------------------------------------
__global__ __launch_bounds__(256) void k_attn(const int* __restrict__ adj,
                                              const unsigned short* __restrict__ hT,
                                              const float* __restrict__ s1g,
                                              const float* __restrict__ s2g,
                                              float* __restrict__ out) {
    __shared__ float s2s[4096];
    __shared__ float accbuf[2][64][17];   // pad 17: conflict-free epilogue
    __shared__ float lbuf[2][64];

    const int tid   = threadIdx.x;
    const int b     = blockIdx.x >> 7;
    const int rtile = blockIdx.x & 127;

    {   // stage s2 row for this batch (16 KB)
        const float* src = s2g + b * 4096;
        #pragma unroll
        for (int t = 0; t < 4; ++t) {
            int idx = tid * 16 + t * 4;
            *(float4*)&s2s[idx] = *(const float4*)(src + idx);
        }
    }
    __syncthreads();

    const int wv    = tid >> 6;
    const int lane  = tid & 63;
    const int jhalf = wv >> 1;
    const int m     = lane & 15;
    const int kh    = lane >> 4;          // 0..3
    const int rbase = rtile * 32 + (wv & 1) * 16;
    const int row   = rbase + m;

    const float s1v = s1g[b * 4096 + row];
    const int jb0 = jhalf * 2048 + kh * 8;
    const int* adjrow = adj + ((size_t)(b * 4096 + row)) * 4096 + jb0;
    const unsigned short* hrow0 = hT + ((size_t)(b * 64 +  0 + m)) * 4096 + jb0;
    const unsigned short* hrow1 = hT + ((size_t)(b * 64 + 16 + m)) * 4096 + jb0;
    const unsigned short* hrow2 = hT + ((size_t)(b * 64 + 32 + m)) * 4096 + jb0;
    const unsigned short* hrow3 = hT + ((size_t)(b * 64 + 48 + m)) * 4096 + jb0;

    floatx4 acc[4];
    #pragma unroll
    for (int f = 0; f < 4; ++f) acc[f] = (floatx4){0.f, 0.f, 0.f, 0.f};
    float lsum = 0.f;

    // software pipeline: prefetch step 0
    int4   padj0 = *(const int4*)(adjrow);
    int4   padj1 = *(const int4*)(adjrow + 4);
    short8 pb0 = *(const short8*)(hrow0);
    short8 pb1 = *(const short8*)(hrow1);
    short8 pb2 = *(const short8*)(hrow2);
    short8 pb3 = *(const short8*)(hrow3);
    float4 ps2a = *(const float4*)&s2s[jb0];
    float4 ps2b = *(const float4*)&s2s[jb0 + 4];

    for (int step = 0; step < 64; ++step) {
        const int4   ca0 = padj0, ca1 = padj1;
        const short8 cb0 = pb0, cb1 = pb1, cb2 = pb2, cb3 = pb3;
        const float4 csa = ps2a, csb = ps2b;

        const int off = ((step + 1) & 63) * 32;   // wrap: no OOB on last iter
        padj0 = *(const int4*)(adjrow + off);
        padj1 = *(const int4*)(adjrow + off + 4);
        pb0 = *(const short8*)(hrow0 + off);
        pb1 = *(const short8*)(hrow1 + off);
        pb2 = *(const short8*)(hrow2 + off);
        pb3 = *(const short8*)(hrow3 + off);
        ps2a = *(const float4*)&s2s[jb0 + off];
        ps2b = *(const float4*)&s2s[jb0 + off + 4];

        const int   av[8] = {ca0.x, ca0.y, ca0.z, ca0.w, ca1.x, ca1.y, ca1.z, ca1.w};
        const float sv[8] = {csa.x, csa.y, csa.z, csa.w, csb.x, csb.y, csb.z, csb.w};

        short8 af;
        float psum = 0.f;
        #pragma unroll
        for (int t = 0; t < 8; ++t) {
            float e = s1v + sv[t];
            e = (e > 0.f) ? e : (LEAKY_ALPHA * e);
            float pv = (av[t] > 0) ? __expf(e) : 0.f;  // no max-sub needed: e bounded
            psum += pv;
            af[t] = (short)f2bf_rne(pv);
        }
        lsum += psum;

        acc[0] = __builtin_amdgcn_mfma_f32_16x16x32_bf16(af, cb0, acc[0], 0, 0, 0);
        acc[1] = __builtin_amdgcn_mfma_f32_16x16x32_bf16(af, cb1, acc[1], 0, 0, 0);
        acc[2] = __builtin_amdgcn_mfma_f32_16x16x32_bf16(af, cb2, acc[2], 0, 0, 0);
        acc[3] = __builtin_amdgcn_mfma_f32_16x16x32_bf16(af, cb3, acc[3], 0, 0, 0);
    }

    // reduce rowsum across the 4 kh-groups: lanes m, m+16, m+32, m+48
    lsum += __shfl_xor(lsum, 16);
    lsum += __shfl_xor(lsum, 32);

    // combine j-halves: waves 2,3 hand off to waves 0,1
    if (wv >= 2) {
        #pragma unroll
        for (int f = 0; f < 4; ++f)
            #pragma unroll
            for (int r = 0; r < 4; ++r)
                accbuf[wv - 2][lane][f * 4 + r] = acc[f][r];
        lbuf[wv - 2][lane] = lsum;
    }
    __syncthreads();
    if (wv < 2) {
        const float ltot = lsum + lbuf[wv][lane];   // rowsum for row = lane&15
        #pragma unroll
        for (int f = 0; f < 4; ++f) {
            #pragma unroll
            for (int r = 0; r < 4; ++r) {
                float v = acc[f][r] + accbuf[wv][lane][f * 4 + r];
                const int drow = (lane >> 4) * 4 + r;       // C/D layout row
                const float lr = __shfl(ltot, drow);        // lane drow holds row drow
                const float hp = v / lr;
                const float o  = (hp > 0.f) ? hp : (__expf(hp) - 1.f);  // elu
                out[((size_t)(b * 4096 + rbase + drow)) * 64 + f * 16 + (lane & 15)] = o;
            }
        }
    }
}

// ---------------------------------------------------------------------------
extern "C" void kernel_launch(void* const* d_in, const int* in_sizes, int n_in,
                              void* d_out, int out_size, void* d_ws, size_t ws_size,
                              hipStream_t stream) {
    const float* inp = (const float*)d_in[0];   // (8,4096,128) fp32
    const int*   adj = (const int*)d_in[1];     // (8,4096,4096) int32
    const float* W   = (const float*)d_in[2];   // (128,64) fp32
    const float* a   = (const float*)d_in[3];   // (128,1) fp32
    float* out = (float*)d_out;                 // (8,4096,64) fp32

    unsigned short* hT = (unsigned short*)d_ws;                    // 4 MiB bf16
    float* s1 = (float*)((char*)d_ws + (size_t)8 * 64 * 4096 * 2); // 128 KB
    float* s2 = s1 + 8 * 4096;                                     // 128 KB

    k_h<<<512, 256, 0, stream>>>(inp, W, a, hT, s1, s2);
    k_attn<<<1024, 256, 0, stream>>>(adj, hT, s1, s2, out);
}